// Round 20
// baseline (330.232 us; speedup 1.0000x reference)
//
#include <hip/hip_runtime.h>

typedef __bf16 bf16x8 __attribute__((ext_vector_type(8)));
typedef __bf16 bf16x4 __attribute__((ext_vector_type(4)));
typedef __bf16 bf16x2 __attribute__((ext_vector_type(2)));
typedef float f32x4 __attribute__((ext_vector_type(4)));
typedef short short4v __attribute__((ext_vector_type(4)));
typedef int i32x2 __attribute__((ext_vector_type(2)));
typedef unsigned u32x2 __attribute__((ext_vector_type(2)));
typedef unsigned u32x4 __attribute__((ext_vector_type(4)));

#define NTOK 98
#define CDIM 128
// LDS = Vtf only (28672 B), aliased by O after barrier 2. Kf lives in GLOBAL scratch:
// the block's own out[win] slice (50176 B >= 28672). Correctness: only this block touches
// the slice; phase-1 stores drain at __syncthreads (vmcnt 0) and are visible via the
// same-XCD L2 (local stores invalidate local L1); phase 3 fully overwrites the slice
// AFTER barrier 2 (all K reads done); dispatch-end L2 writeback covers graph replays.
#define SM_TOTAL 28672
#define QSCALE 0.2550181952219662f   // hd^-0.5 * log2(e)
#define LOG2E  1.4426950408889634f

#if defined(__has_builtin)
#if __has_builtin(__builtin_amdgcn_exp2f)
#define EXP2F(x) __builtin_amdgcn_exp2f(x)
#else
#define EXP2F(x) exp2f(x)
#endif
#if __has_builtin(__builtin_amdgcn_rcpf)
#define RCPF(x) __builtin_amdgcn_rcpf(x)
#else
#define RCPF(x) (1.f / (x))
#endif
#else
#define EXP2F(x) exp2f(x)
#define RCPF(x) (1.f / (x))
#endif

__device__ __forceinline__ f32x4 mfma32(bf16x8 a, bf16x8 b, f32x4 c) {
  return __builtin_amdgcn_mfma_f32_16x16x32_bf16(a, b, c, 0, 0, 0);
}

__device__ __forceinline__ f32x4 mfma16(bf16x4 a, bf16x4 b, f32x4 c) {
#if defined(__has_builtin) && __has_builtin(__builtin_amdgcn_mfma_f32_16x16x16bf16_1k)
  return __builtin_amdgcn_mfma_f32_16x16x16bf16_1k(__builtin_bit_cast(short4v, a),
                                                   __builtin_bit_cast(short4v, b), c, 0, 0, 0);
#elif defined(__has_builtin) && __has_builtin(__builtin_amdgcn_mfma_f32_16x16x16_bf16)
  return __builtin_amdgcn_mfma_f32_16x16x16_bf16(a, b, c, 0, 0, 0);
#else
  f32x4 d;
  i32x2 ai = __builtin_bit_cast(i32x2, a), bi = __builtin_bit_cast(i32x2, b);
  asm volatile("v_mfma_f32_16x16x16_bf16 %0, %1, %2, %3"
               : "=&v"(d) : "v"(ai), "v"(bi), "v"(c));
  return d;
#endif
}

__device__ __forceinline__ unsigned pk2(float a, float b) {
  bf16x2 t; t[0] = (__bf16)a; t[1] = (__bf16)b;
  return __builtin_bit_cast(unsigned, t);
}

// ---------------- precompute: frag-ordered weights + frag-ordered mask/bias tables ----------------
__global__ void precompute_k(const float* __restrict__ qkv_w, const float* __restrict__ proj_w,
                             const float* __restrict__ bias_table, const int* __restrict__ rel_index,
                             const float* __restrict__ mask,
                             __bf16* __restrict__ wkT, __bf16* __restrict__ wvf,
                             __bf16* __restrict__ wqT, __bf16* __restrict__ wproj,
                             float* __restrict__ biasf, float* __restrict__ maskf) {
  int t = blockIdx.x * blockDim.x + threadIdx.x;
  int stride = gridDim.x * blockDim.x;
  // wqT/wkT A-frag & wvf B-frag: [cb(8)][kk(4)][lane(64)][8]
  for (int g = t; g < 8 * 4 * 64; g += stride) {
    int cb = g >> 8, kk = (g >> 6) & 3, lane = g & 63;
    int co = cb * 16 + (lane & 15);
    int ci0 = kk * 32 + (lane >> 4) * 8;
    __bf16 *dq = wqT + g * 8, *dk = wkT + g * 8, *dv = wvf + g * 8;
#pragma unroll
    for (int e = 0; e < 8; ++e) {
      const float* r = qkv_w + (size_t)(ci0 + e) * 384;
      dq[e] = (__bf16)r[co];
      dk[e] = (__bf16)r[128 + co];
      dv[e] = (__bf16)r[256 + co];
    }
  }
  // wproj B-frag: [nt(8)][kk(4)][lane][8]
  for (int g = t; g < 8 * 4 * 64; g += stride) {
    int nt = g >> 8, kk = (g >> 6) & 3, lane = g & 63;
    int n = nt * 16 + (lane & 15);
    int k0 = kk * 32 + (lane >> 4) * 8;
    __bf16* dst = wproj + g * 8;
#pragma unroll
    for (int e = 0; e < 8; ++e) dst[e] = (__bf16)proj_w[(k0 + e) * 128 + n];
  }
  // biasf [h(4)][m(7)][nt(7)][lane][4]: query=m*16+(lane&15), key=nt*16+(lane>>4)*4+j
  for (int g = t; g < 4 * 49 * 64; g += stride) {
    int h = g / (49 * 64), r = g % (49 * 64);
    int m = r / (7 * 64), r2 = r % (7 * 64);
    int nt = r2 / 64, lane = r2 % 64;
    int q = m * 16 + (lane & 15), k0 = nt * 16 + (lane >> 4) * 4;
    float* dst = biasf + g * 4;
#pragma unroll
    for (int j = 0; j < 4; ++j) {
      int key = k0 + j;
      dst[j] = (key < NTOK && q < NTOK) ? bias_table[rel_index[q * NTOK + key] * 4 + h] * LOG2E : 0.f;
    }
  }
  // maskf [wm(64)][m(7)][nt(7)][lane][4]
  for (int g = t; g < 64 * 49 * 64; g += stride) {
    int wm = g / (49 * 64), r = g % (49 * 64);
    int m = r / (7 * 64), r2 = r % (7 * 64);
    int nt = r2 / 64, lane = r2 % 64;
    int q = m * 16 + (lane & 15), k0 = nt * 16 + (lane >> 4) * 4;
    float* dst = maskf + g * 4;
#pragma unroll
    for (int j = 0; j < 4; ++j) {
      int key = k0 + j;
      float v;
      if (key >= NTOK) v = -1e30f;
      else if (q >= NTOK) v = 0.f;
      else v = mask[wm * (NTOK * NTOK) + q * NTOK + key] * LOG2E;
      dst[j] = v;
    }
  }
}

// ---------------- fused window attention: 512 thr (8 waves), 28.7KB LDS -> up to 4 blocks/CU ----------------
__launch_bounds__(512, 4)
__global__ void wattn_k(const float* __restrict__ x,
                        const float* __restrict__ qkv_b, const float* __restrict__ proj_b,
                        const __bf16* __restrict__ wkT, const __bf16* __restrict__ wvf,
                        const __bf16* __restrict__ wqT, const __bf16* __restrict__ wproj,
                        const float* __restrict__ biasf, const float* __restrict__ maskf,
                        float* __restrict__ out) {
  extern __shared__ char smem[];
  __bf16* const Vtf = (__bf16*)smem;   // [7][8][64][4] frag order; aliased by O [112][128] after barrier 2

  // XCD-aware swizzle (R18: FETCH -29%; also keeps K-scratch traffic XCD-local)
  const int braw = blockIdx.x;
  const int xcd  = braw & 7;
  const int bidx = braw >> 3;
  const int b    = (bidx >> 3) * 64 + xcd * 8 + (bidx & 7);

  const int tid  = threadIdx.x;
  const int w    = tid >> 6;
  const int lane = tid & 63;
  const int l15  = lane & 15;
  const int l4   = lane >> 4;
  const float* xw = x + (size_t)b * (NTOK * CDIM);
  char* const Kg  = (char*)(out + (size_t)b * (NTOK * CDIM));   // K frag scratch: [m(7)][g(4)][64][16B]

  const bool act = (w < 7);
  const int m    = act ? w : 0;
  const int mb   = m << 4;

  bf16x8 bq[4];        // ONLY value crossing barrier 1 (4 heads x B-frag)
  if (act) {
    // ---- load this wave's x fragment (rows mb..mb+15 clamped, all 128 ch) ----
    bf16x8 xf[4];
    {
      int row = mb + l15;
      int rowc = (row < NTOK) ? row : (NTOK - 1);
      const float* xrow = xw + (size_t)rowc * CDIM;
#pragma unroll
      for (int kk = 0; kk < 4; ++kk) {
        float4 u0 = *(const float4*)(xrow + kk * 32 + l4 * 8);
        float4 u1 = *(const float4*)(xrow + kk * 32 + l4 * 8 + 4);
        bf16x8 v;
        v[0] = (__bf16)u0.x; v[1] = (__bf16)u0.y; v[2] = (__bf16)u0.z; v[3] = (__bf16)u0.w;
        v[4] = (__bf16)u1.x; v[5] = (__bf16)u1.y; v[6] = (__bf16)u1.z; v[7] = (__bf16)u1.w;
        xf[kk] = v;
      }
    }
    // ---- Q^T for ALL 128 channels (8 tiles), transposed to B-frags (pk dies here) ----
    {
      unsigned pk[8][2];
#pragma unroll
      for (int cbl = 0; cbl < 8; ++cbl) {
        float4 qb4 = *(const float4*)(qkv_b + cbl * 16 + (l4 << 2));
        f32x4 acc = {qb4.x, qb4.y, qb4.z, qb4.w};
#pragma unroll
        for (int kk = 0; kk < 4; ++kk) {
          bf16x8 wq8 = *(const bf16x8*)(wqT + ((cbl * 4 + kk) * 64 + lane) * 8);
          acc = mfma32(wq8, xf[kk], acc);
        }
        pk[cbl][0] = pk2(acc[0] * QSCALE, acc[1] * QSCALE);
        pk[cbl][1] = pk2(acc[2] * QSCALE, acc[3] * QSCALE);
      }
      // bpermute BOTH candidate groups, select at DESTINATION
#pragma unroll
      for (int h = 0; h < 4; ++h) {
        unsigned d[4];
#pragma unroll
        for (int dd = 0; dd < 4; ++dd) {
          int srcl = (((l4 & 1) * 2 + (dd >> 1)) * 16 + l15) << 2;
          unsigned lo = (unsigned)__builtin_amdgcn_ds_bpermute(srcl, (int)pk[h * 2][dd & 1]);
          unsigned hi = (unsigned)__builtin_amdgcn_ds_bpermute(srcl, (int)pk[h * 2 + 1][dd & 1]);
          d[dd] = (l4 >= 2) ? hi : lo;
        }
        u32x4 du = {d[0], d[1], d[2], d[3]};
        bq[h] = __builtin_bit_cast(bf16x8, du);
      }
    }
    // ---- K^T (swapped) -> GLOBAL scratch, V (unswapped) -> LDS (xf dies here) ----
#pragma unroll 1
    for (int cb = 0; cb < 8; ++cb) {
      float4 bk4 = *(const float4*)(qkv_b + 128 + cb * 16 + (l4 << 2));
      f32x4 ak = {bk4.x, bk4.y, bk4.z, bk4.w};
      float bv1 = qkv_b[256 + cb * 16 + l15];
      f32x4 av = {bv1, bv1, bv1, bv1};
#pragma unroll
      for (int kk = 0; kk < 4; ++kk) {
        bf16x8 wk8 = *(const bf16x8*)(wkT + ((cb * 4 + kk) * 64 + lane) * 8);
        bf16x8 wv8 = *(const bf16x8*)(wvf + ((cb * 4 + kk) * 64 + lane) * 8);
        ak = mfma32(wk8, xf[kk], ak);      // K^T tile: (ch, token)
        av = mfma32(xf[kk], wv8, av);      // V tile:  (token, ch)
      }
      {  // Kg: lane'' = ((cb&1)*2 + (l4>>1))*16 + l15 ; byte = (tile_lane)*16 + (l4&1)*8
        u32x2 u; u[0] = pk2(ak[0], ak[1]); u[1] = pk2(ak[2], ak[3]);
        int boff = ((m * 4 + (cb >> 1)) * 64 + ((cb & 1) * 2 + (l4 >> 1)) * 16 + l15) * 16 + (l4 & 1) * 8;
        *reinterpret_cast<u32x2*>(Kg + boff) = u;
      }
      {  // Vtf: same lane, elems j
        u32x2 u; u[0] = pk2(av[0], av[1]); u[1] = pk2(av[2], av[3]);
        int idx = ((m * 8 + cb) * 64 + lane) * 4;
        *reinterpret_cast<u32x2*>(Vtf + idx) = u;
      }
    }
  }
  __syncthreads();   // barrier 1: drains vmcnt -> K scratch visible via L2; V visible in LDS

  // ---- phase 2: swapped QK^T (C-init = maskf, + biasf), in-reg softmax, swapped PV; 4 heads ----
  u32x2 accOp[4][2];   // ONLY value crossing barrier 2 (statically indexed: h loop unrolled)
  if (act) {
    const int wm = b & 63;
    const float* mrow = maskf + ((size_t)(wm * 49 + m * 7)) * 256 + lane * 4;
#pragma unroll
    for (int h = 0; h < 4; ++h) {
      const float* brow = biasf + ((size_t)(h * 49 + m * 7)) * 256 + lane * 4;
      bf16x4 pw[7];
      float rsum = 0.f;
#pragma unroll
      for (int nt = 0; nt < 7; ++nt) {
        f32x4 c4 = *(const f32x4*)(mrow + nt * 256);
        bf16x8 ak8 = *(const bf16x8*)(Kg + (((nt * 4 + h) * 64 + lane) * 16));
        f32x4 s = mfma32(ak8, bq[h], c4);            // (key, query) tile
        f32x4 bb = *(const f32x4*)(brow + nt * 256);
        float p0 = EXP2F(s[0] + bb[0]), p1 = EXP2F(s[1] + bb[1]);
        float p2 = EXP2F(s[2] + bb[2]), p3 = EXP2F(s[3] + bb[3]);
        rsum += (p0 + p1) + (p2 + p3);
        u32x2 u; u[0] = pk2(p0, p1); u[1] = pk2(p2, p3);
        pw[nt] = __builtin_bit_cast(bf16x4, u);
      }
      rsum += __shfl_xor(rsum, 16, 64);
      rsum += __shfl_xor(rsum, 32, 64);
      float inv = RCPF(rsum);                        // this lane's query (l15) row sum
#pragma unroll
      for (int cb2 = 0; cb2 < 2; ++cb2) {
        f32x4 acc = {0.f, 0.f, 0.f, 0.f};
#pragma unroll
        for (int nt = 0; nt < 7; ++nt) {
          bf16x4 vb = *(const bf16x4*)(Vtf + ((nt * 8 + h * 2 + cb2) * 64 + lane) * 4);
          acc = mfma16(vb, pw[nt], acc);             // O^T: (ch, query)
        }
        u32x2 u; u[0] = pk2(acc[0] * inv, acc[1] * inv); u[1] = pk2(acc[2] * inv, acc[3] * inv);
        accOp[h][cb2] = u;
      }
    }
  }
  __syncthreads();   // barrier 2: all V(LDS)+K(global) reads complete -> smem reusable as O; out overwritable
  if (act) {
    int row = mb + l15;
    unsigned swz = (unsigned)((row & 7) << 4);
#pragma unroll
    for (int h = 0; h < 4; ++h) {
#pragma unroll
      for (int cb2 = 0; cb2 < 2; ++cb2) {
        unsigned boff = (unsigned)(row * 256 + (h * 32 + cb2 * 16 + l4 * 4) * 2) ^ swz;
        *reinterpret_cast<u32x2*>(smem + boff) = accOp[h][cb2];
      }
    }
  }
  __syncthreads();

  // ---- phase 3: out = O @ wproj + proj_b  (O = smem, [112][128] XOR-swizzled); 8 waves ----
  {
    float* outw = out + (size_t)b * (NTOK * CDIM);
    int mt = w % 7, nt2 = w / 7;
    for (int pt = w; pt < 28; pt += 8) {
      const int mb3 = mt << 4;
      const int ntA = nt2 << 1;
      int row = mb3 + l15;
      unsigned swz = (unsigned)((row & 7) << 4);
      f32x4 accA = {0.f, 0.f, 0.f, 0.f};
      f32x4 accB = {0.f, 0.f, 0.f, 0.f};
#pragma unroll
      for (int kk = 0; kk < 4; ++kk) {
        unsigned boff = (unsigned)(row * 256 + kk * 64 + l4 * 16) ^ swz;
        bf16x8 a  = *(const bf16x8*)(smem + boff);
        bf16x8 b0 = *(const bf16x8*)(wproj + (((ntA << 2) + kk) * 64 + lane) * 8);
        bf16x8 b1 = *(const bf16x8*)(wproj + ((((ntA + 1) << 2) + kk) * 64 + lane) * 8);
        accA = mfma32(a, b0, accA);
        accB = mfma32(a, b1, accB);
      }
#pragma unroll
      for (int u = 0; u < 2; ++u) {
        f32x4 acc = u ? accB : accA;
        int n = ((ntA + u) << 4) + l15;
        float pb = proj_b[n];
#pragma unroll
        for (int j = 0; j < 4; ++j) {
          int i = mb3 + (l4 << 2) + j;
          if (i < NTOK) outw[i * CDIM + n] = acc[j] + pb;
        }
      }
      mt += 1; nt2 += 1;
      if (mt >= 7) { mt -= 7; ++nt2; }
    }
  }
}

extern "C" void kernel_launch(void* const* d_in, const int* in_sizes, int n_in,
                              void* d_out, int out_size, void* d_ws, size_t ws_size,
                              hipStream_t stream) {
  const float* x        = (const float*)d_in[0];
  const float* mask     = (const float*)d_in[1];
  const float* qkv_w    = (const float*)d_in[2];
  const float* qkv_b    = (const float*)d_in[3];
  const float* proj_w   = (const float*)d_in[4];
  const float* proj_b   = (const float*)d_in[5];
  const float* bias_tab = (const float*)d_in[6];
  const int*   rel_idx  = (const int*)d_in[7];
  float* out = (float*)d_out;

  char* ws = (char*)d_ws;
  __bf16* wkT   = (__bf16*)(ws + 0);        // 32768
  __bf16* wvf   = (__bf16*)(ws + 32768);    // 32768
  __bf16* wqT   = (__bf16*)(ws + 65536);    // 32768
  __bf16* wproj = (__bf16*)(ws + 98304);    // 32768
  float*  biasf = (float*)(ws + 131072);    // 200704
  float*  maskf = (float*)(ws + 331776);    // 3211264  (total ~3.54 MB)

  precompute_k<<<512, 256, 0, stream>>>(qkv_w, proj_w, bias_tab, rel_idx, mask,
                                        wkT, wvf, wqT, wproj, biasf, maskf);

  hipFuncSetAttribute(reinterpret_cast<const void*>(wattn_k),
                      hipFuncAttributeMaxDynamicSharedMemorySize, SM_TOTAL);
  wattn_k<<<4096, 512, SM_TOTAL, stream>>>(x, qkv_b, proj_b, wkT, wvf, wqT, wproj,
                                           biasf, maskf, out);
}

// Round 21
// 240.869 us; speedup vs baseline: 1.3710x; 1.3710x over previous
//
#include <hip/hip_runtime.h>

typedef __bf16 bf16x8 __attribute__((ext_vector_type(8)));
typedef __bf16 bf16x4 __attribute__((ext_vector_type(4)));
typedef __bf16 bf16x2 __attribute__((ext_vector_type(2)));
typedef float f32x4 __attribute__((ext_vector_type(4)));
typedef short short4v __attribute__((ext_vector_type(4)));
typedef int i32x2 __attribute__((ext_vector_type(2)));
typedef unsigned u32x2 __attribute__((ext_vector_type(2)));
typedef unsigned u32x4 __attribute__((ext_vector_type(4)));

#define NTOK 98
#define CDIM 128
#define SM_TOTAL 57344            // Kf 28672 (aliased by O [112][128] swizzled) + Vtf 28672
#define QSCALE 0.2550181952219662f   // hd^-0.5 * log2(e)
#define LOG2E  1.4426950408889634f

#if defined(__has_builtin)
#if __has_builtin(__builtin_amdgcn_exp2f)
#define EXP2F(x) __builtin_amdgcn_exp2f(x)
#else
#define EXP2F(x) exp2f(x)
#endif
#if __has_builtin(__builtin_amdgcn_rcpf)
#define RCPF(x) __builtin_amdgcn_rcpf(x)
#else
#define RCPF(x) (1.f / (x))
#endif
#else
#define EXP2F(x) exp2f(x)
#define RCPF(x) (1.f / (x))
#endif

__device__ __forceinline__ f32x4 mfma32(bf16x8 a, bf16x8 b, f32x4 c) {
  return __builtin_amdgcn_mfma_f32_16x16x32_bf16(a, b, c, 0, 0, 0);
}

__device__ __forceinline__ f32x4 mfma16(bf16x4 a, bf16x4 b, f32x4 c) {
#if defined(__has_builtin) && __has_builtin(__builtin_amdgcn_mfma_f32_16x16x16bf16_1k)
  return __builtin_amdgcn_mfma_f32_16x16x16bf16_1k(__builtin_bit_cast(short4v, a),
                                                   __builtin_bit_cast(short4v, b), c, 0, 0, 0);
#elif defined(__has_builtin) && __has_builtin(__builtin_amdgcn_mfma_f32_16x16x16_bf16)
  return __builtin_amdgcn_mfma_f32_16x16x16_bf16(a, b, c, 0, 0, 0);
#else
  f32x4 d;
  i32x2 ai = __builtin_bit_cast(i32x2, a), bi = __builtin_bit_cast(i32x2, b);
  asm volatile("v_mfma_f32_16x16x16_bf16 %0, %1, %2, %3"
               : "=&v"(d) : "v"(ai), "v"(bi), "v"(c));
  return d;
#endif
}

__device__ __forceinline__ unsigned pk2(float a, float b) {
  bf16x2 t; t[0] = (__bf16)a; t[1] = (__bf16)b;
  return __builtin_bit_cast(unsigned, t);
}

// ---------------- precompute: frag-ordered weights + frag-ordered mask/bias tables ----------------
__global__ void precompute_k(const float* __restrict__ qkv_w, const float* __restrict__ proj_w,
                             const float* __restrict__ bias_table, const int* __restrict__ rel_index,
                             const float* __restrict__ mask,
                             __bf16* __restrict__ wkT, __bf16* __restrict__ wvf,
                             __bf16* __restrict__ wqT, __bf16* __restrict__ wproj,
                             float* __restrict__ biasf, float* __restrict__ maskf) {
  int t = blockIdx.x * blockDim.x + threadIdx.x;
  int stride = gridDim.x * blockDim.x;
  // wqT/wkT A-frag & wvf B-frag: [cb(8)][kk(4)][lane(64)][8]
  for (int g = t; g < 8 * 4 * 64; g += stride) {
    int cb = g >> 8, kk = (g >> 6) & 3, lane = g & 63;
    int co = cb * 16 + (lane & 15);
    int ci0 = kk * 32 + (lane >> 4) * 8;
    __bf16 *dq = wqT + g * 8, *dk = wkT + g * 8, *dv = wvf + g * 8;
#pragma unroll
    for (int e = 0; e < 8; ++e) {
      const float* r = qkv_w + (size_t)(ci0 + e) * 384;
      dq[e] = (__bf16)r[co];
      dk[e] = (__bf16)r[128 + co];
      dv[e] = (__bf16)r[256 + co];
    }
  }
  // wproj B-frag: [nt(8)][kk(4)][lane][8]
  for (int g = t; g < 8 * 4 * 64; g += stride) {
    int nt = g >> 8, kk = (g >> 6) & 3, lane = g & 63;
    int n = nt * 16 + (lane & 15);
    int k0 = kk * 32 + (lane >> 4) * 8;
    __bf16* dst = wproj + g * 8;
#pragma unroll
    for (int e = 0; e < 8; ++e) dst[e] = (__bf16)proj_w[(k0 + e) * 128 + n];
  }
  // biasf [h(4)][m(7)][nt(7)][lane][4]: query=m*16+(lane&15), key=nt*16+(lane>>4)*4+j
  for (int g = t; g < 4 * 49 * 64; g += stride) {
    int h = g / (49 * 64), r = g % (49 * 64);
    int m = r / (7 * 64), r2 = r % (7 * 64);
    int nt = r2 / 64, lane = r2 % 64;
    int q = m * 16 + (lane & 15), k0 = nt * 16 + (lane >> 4) * 4;
    float* dst = biasf + g * 4;
#pragma unroll
    for (int j = 0; j < 4; ++j) {
      int key = k0 + j;
      dst[j] = (key < NTOK && q < NTOK) ? bias_table[rel_index[q * NTOK + key] * 4 + h] * LOG2E : 0.f;
    }
  }
  // maskf [wm(64)][m(7)][nt(7)][lane][4]
  for (int g = t; g < 64 * 49 * 64; g += stride) {
    int wm = g / (49 * 64), r = g % (49 * 64);
    int m = r / (7 * 64), r2 = r % (7 * 64);
    int nt = r2 / 64, lane = r2 % 64;
    int q = m * 16 + (lane & 15), k0 = nt * 16 + (lane >> 4) * 4;
    float* dst = maskf + g * 4;
#pragma unroll
    for (int j = 0; j < 4; ++j) {
      int key = k0 + j;
      float v;
      if (key >= NTOK) v = -1e30f;
      else if (q >= NTOK) v = 0.f;
      else v = mask[wm * (NTOK * NTOK) + q * NTOK + key] * LOG2E;
      dst[j] = v;
    }
  }
}

// ---------------- fused window attention: 512 thr (8 waves), 57KB LDS -> 2 blocks/CU ----------------
// Best verified configuration (R18: 266us kernel / 242us wall). Waves 0-6 own m-tile w
// (all 4 heads); XCD-aware window swizzle keeps per-XCD maskf slice L2-resident.
// launch_bounds(512,4): 128-VGPR cap (tighter caps spill catastrophically; R12/R14).
// Occupancy ceiling is the unified-file register total (~4 waves/SIMD) — LDS diets
// (50KB, 28KB) and bigger blocks did NOT raise it (R15/R19/R20).
__launch_bounds__(512, 4)
__global__ void wattn_k(const float* __restrict__ x,
                        const float* __restrict__ qkv_b, const float* __restrict__ proj_b,
                        const __bf16* __restrict__ wkT, const __bf16* __restrict__ wvf,
                        const __bf16* __restrict__ wqT, const __bf16* __restrict__ wproj,
                        const float* __restrict__ biasf, const float* __restrict__ maskf,
                        float* __restrict__ out) {
  extern __shared__ char smem[];
  __bf16* const Kf  = (__bf16*)smem;            // [7][4][64][8] frag order; later O [112][128] XOR-swizzled
  __bf16* const Vtf = (__bf16*)(smem + 28672);  // [7][8][64][4] frag order

  // XCD-aware swizzle: bijective remap blockIdx -> window index.
  // i = b&7 (XCD), idx = b>>3; win = (idx>>3)*64 + i*8 + (idx&7); wm = i*8 + (idx&7).
  const int braw = blockIdx.x;
  const int xcd  = braw & 7;
  const int bidx = braw >> 3;
  const int b    = (bidx >> 3) * 64 + xcd * 8 + (bidx & 7);

  const int tid  = threadIdx.x;
  const int w    = tid >> 6;
  const int lane = tid & 63;
  const int l15  = lane & 15;
  const int l4   = lane >> 4;
  const float* xw = x + (size_t)b * (NTOK * CDIM);

  const bool act = (w < 7);
  const int m    = act ? w : 0;
  const int mb   = m << 4;

  bf16x8 bq[4];        // ONLY value crossing barrier 1 (4 heads x B-frag)
  if (act) {
    // ---- load this wave's x fragment (rows mb..mb+15 clamped, all 128 ch) ----
    bf16x8 xf[4];
    {
      int row = mb + l15;
      int rowc = (row < NTOK) ? row : (NTOK - 1);
      const float* xrow = xw + (size_t)rowc * CDIM;
#pragma unroll
      for (int kk = 0; kk < 4; ++kk) {
        float4 u0 = *(const float4*)(xrow + kk * 32 + l4 * 8);
        float4 u1 = *(const float4*)(xrow + kk * 32 + l4 * 8 + 4);
        bf16x8 v;
        v[0] = (__bf16)u0.x; v[1] = (__bf16)u0.y; v[2] = (__bf16)u0.z; v[3] = (__bf16)u0.w;
        v[4] = (__bf16)u1.x; v[5] = (__bf16)u1.y; v[6] = (__bf16)u1.z; v[7] = (__bf16)u1.w;
        xf[kk] = v;
      }
    }
    // ---- Q^T for ALL 128 channels (8 tiles), transposed to B-frags (pk dies here) ----
    {
      unsigned pk[8][2];
#pragma unroll
      for (int cbl = 0; cbl < 8; ++cbl) {
        float4 qb4 = *(const float4*)(qkv_b + cbl * 16 + (l4 << 2));
        f32x4 acc = {qb4.x, qb4.y, qb4.z, qb4.w};
#pragma unroll
        for (int kk = 0; kk < 4; ++kk) {
          bf16x8 wq8 = *(const bf16x8*)(wqT + ((cbl * 4 + kk) * 64 + lane) * 8);
          acc = mfma32(wq8, xf[kk], acc);
        }
        pk[cbl][0] = pk2(acc[0] * QSCALE, acc[1] * QSCALE);
        pk[cbl][1] = pk2(acc[2] * QSCALE, acc[3] * QSCALE);
      }
      // bpermute BOTH candidate groups, select at DESTINATION (bpermute pulls the source
      // lane's operand; the group choice depends on the destination lane's l4)
#pragma unroll
      for (int h = 0; h < 4; ++h) {
        unsigned d[4];
#pragma unroll
        for (int dd = 0; dd < 4; ++dd) {
          int srcl = (((l4 & 1) * 2 + (dd >> 1)) * 16 + l15) << 2;
          unsigned lo = (unsigned)__builtin_amdgcn_ds_bpermute(srcl, (int)pk[h * 2][dd & 1]);
          unsigned hi = (unsigned)__builtin_amdgcn_ds_bpermute(srcl, (int)pk[h * 2 + 1][dd & 1]);
          d[dd] = (l4 >= 2) ? hi : lo;
        }
        u32x4 du = {d[0], d[1], d[2], d[3]};
        bq[h] = __builtin_bit_cast(bf16x8, du);
      }
    }
    // ---- K^T (swapped) and V (unswapped) tiles (m, cb=0..7) -> LDS (xf dies here) ----
#pragma unroll 1
    for (int cb = 0; cb < 8; ++cb) {
      float4 bk4 = *(const float4*)(qkv_b + 128 + cb * 16 + (l4 << 2));
      f32x4 ak = {bk4.x, bk4.y, bk4.z, bk4.w};
      float bv1 = qkv_b[256 + cb * 16 + l15];
      f32x4 av = {bv1, bv1, bv1, bv1};
#pragma unroll
      for (int kk = 0; kk < 4; ++kk) {
        bf16x8 wk8 = *(const bf16x8*)(wkT + ((cb * 4 + kk) * 64 + lane) * 8);
        bf16x8 wv8 = *(const bf16x8*)(wvf + ((cb * 4 + kk) * 64 + lane) * 8);
        ak = mfma32(wk8, xf[kk], ak);      // K^T tile: (ch, token)
        av = mfma32(xf[kk], wv8, av);      // V tile:  (token, ch)
      }
      {  // Kf: lane'' = ((cb&1)*2 + (l4>>1))*16 + l15 ; elems (l4&1)*4 + j
        u32x2 u; u[0] = pk2(ak[0], ak[1]); u[1] = pk2(ak[2], ak[3]);
        int idx = ((m * 4 + (cb >> 1)) * 64 + ((cb & 1) * 2 + (l4 >> 1)) * 16 + l15) * 8 + (l4 & 1) * 4;
        *reinterpret_cast<u32x2*>(Kf + idx) = u;
      }
      {  // Vtf: same lane, elems j
        u32x2 u; u[0] = pk2(av[0], av[1]); u[1] = pk2(av[2], av[3]);
        int idx = ((m * 8 + cb) * 64 + lane) * 4;
        *reinterpret_cast<u32x2*>(Vtf + idx) = u;
      }
    }
  }
  __syncthreads();

  // ---- phase 2: swapped QK^T (C-init = maskf, + biasf), in-reg softmax, swapped PV; 4 heads ----
  u32x2 accOp[4][2];   // ONLY value crossing barrier 2 (statically indexed: h loop unrolled)
  if (act) {
    const int wm = b & 63;
    const float* mrow = maskf + ((size_t)(wm * 49 + m * 7)) * 256 + lane * 4;
#pragma unroll
    for (int h = 0; h < 4; ++h) {
      const float* brow = biasf + ((size_t)(h * 49 + m * 7)) * 256 + lane * 4;
      bf16x4 pw[7];
      float rsum = 0.f;
#pragma unroll
      for (int nt = 0; nt < 7; ++nt) {
        f32x4 c4 = *(const f32x4*)(mrow + nt * 256);
        bf16x8 ak8 = *(const bf16x8*)(Kf + ((nt * 4 + h) * 64 + lane) * 8);
        f32x4 s = mfma32(ak8, bq[h], c4);            // (key, query) tile
        f32x4 bb = *(const f32x4*)(brow + nt * 256);
        float p0 = EXP2F(s[0] + bb[0]), p1 = EXP2F(s[1] + bb[1]);
        float p2 = EXP2F(s[2] + bb[2]), p3 = EXP2F(s[3] + bb[3]);
        rsum += (p0 + p1) + (p2 + p3);
        u32x2 u; u[0] = pk2(p0, p1); u[1] = pk2(p2, p3);
        pw[nt] = __builtin_bit_cast(bf16x4, u);
      }
      rsum += __shfl_xor(rsum, 16, 64);
      rsum += __shfl_xor(rsum, 32, 64);
      float inv = RCPF(rsum);                        // this lane's query (l15) row sum
#pragma unroll
      for (int cb2 = 0; cb2 < 2; ++cb2) {
        f32x4 acc = {0.f, 0.f, 0.f, 0.f};
#pragma unroll
        for (int nt = 0; nt < 7; ++nt) {
          bf16x4 vb = *(const bf16x4*)(Vtf + ((nt * 8 + h * 2 + cb2) * 64 + lane) * 4);
          acc = mfma16(vb, pw[nt], acc);             // O^T: (ch, query)
        }
        u32x2 u; u[0] = pk2(acc[0] * inv, acc[1] * inv); u[1] = pk2(acc[2] * inv, acc[3] * inv);
        accOp[h][cb2] = u;
      }
    }
  }
  __syncthreads();   // all Kf reads complete -> safe to overwrite with O
  if (act) {
    int row = mb + l15;
    unsigned swz = (unsigned)((row & 7) << 4);
#pragma unroll
    for (int h = 0; h < 4; ++h) {
#pragma unroll
      for (int cb2 = 0; cb2 < 2; ++cb2) {
        unsigned boff = (unsigned)(row * 256 + (h * 32 + cb2 * 16 + l4 * 4) * 2) ^ swz;
        *reinterpret_cast<u32x2*>(smem + boff) = accOp[h][cb2];
      }
    }
  }
  __syncthreads();

  // ---- phase 3: out = O @ wproj + proj_b  (O = smem, [112][128] XOR-swizzled); 8 waves ----
  {
    float* outw = out + (size_t)b * (NTOK * CDIM);
    int mt = w % 7, nt2 = w / 7;
    for (int pt = w; pt < 28; pt += 8) {
      const int mb3 = mt << 4;
      const int ntA = nt2 << 1;
      int row = mb3 + l15;
      unsigned swz = (unsigned)((row & 7) << 4);
      f32x4 accA = {0.f, 0.f, 0.f, 0.f};
      f32x4 accB = {0.f, 0.f, 0.f, 0.f};
#pragma unroll
      for (int kk = 0; kk < 4; ++kk) {
        unsigned boff = (unsigned)(row * 256 + kk * 64 + l4 * 16) ^ swz;
        bf16x8 a  = *(const bf16x8*)(smem + boff);
        bf16x8 b0 = *(const bf16x8*)(wproj + (((ntA << 2) + kk) * 64 + lane) * 8);
        bf16x8 b1 = *(const bf16x8*)(wproj + ((((ntA + 1) << 2) + kk) * 64 + lane) * 8);
        accA = mfma32(a, b0, accA);
        accB = mfma32(a, b1, accB);
      }
#pragma unroll
      for (int u = 0; u < 2; ++u) {
        f32x4 acc = u ? accB : accA;
        int n = ((ntA + u) << 4) + l15;
        float pb = proj_b[n];
#pragma unroll
        for (int j = 0; j < 4; ++j) {
          int i = mb3 + (l4 << 2) + j;
          if (i < NTOK) outw[i * CDIM + n] = acc[j] + pb;
        }
      }
      mt += 1; nt2 += 1;
      if (mt >= 7) { mt -= 7; ++nt2; }
    }
  }
}

extern "C" void kernel_launch(void* const* d_in, const int* in_sizes, int n_in,
                              void* d_out, int out_size, void* d_ws, size_t ws_size,
                              hipStream_t stream) {
  const float* x        = (const float*)d_in[0];
  const float* mask     = (const float*)d_in[1];
  const float* qkv_w    = (const float*)d_in[2];
  const float* qkv_b    = (const float*)d_in[3];
  const float* proj_w   = (const float*)d_in[4];
  const float* proj_b   = (const float*)d_in[5];
  const float* bias_tab = (const float*)d_in[6];
  const int*   rel_idx  = (const int*)d_in[7];
  float* out = (float*)d_out;

  char* ws = (char*)d_ws;
  __bf16* wkT   = (__bf16*)(ws + 0);        // 32768
  __bf16* wvf   = (__bf16*)(ws + 32768);    // 32768
  __bf16* wqT   = (__bf16*)(ws + 65536);    // 32768
  __bf16* wproj = (__bf16*)(ws + 98304);    // 32768
  float*  biasf = (float*)(ws + 131072);    // 200704
  float*  maskf = (float*)(ws + 331776);    // 3211264  (total ~3.54 MB)

  precompute_k<<<512, 256, 0, stream>>>(qkv_w, proj_w, bias_tab, rel_idx, mask,
                                        wkT, wvf, wqT, wproj, biasf, maskf);

  hipFuncSetAttribute(reinterpret_cast<const void*>(wattn_k),
                      hipFuncAttributeMaxDynamicSharedMemorySize, SM_TOTAL);
  wattn_k<<<4096, 512, SM_TOTAL, stream>>>(x, qkv_b, proj_b, wkT, wvf, wqT, wproj,
                                           biasf, maskf, out);
}